// Round 7
// baseline (401.171 us; speedup 1.0000x reference)
//
#include <hip/hip_runtime.h>
#include <stdint.h>

// ---------------------------------------------------------------------------
// DistributedAttention on MI355X (gfx950)
//   q = x Wq^T + bq ; k = x Wk^T + bk ; v = x Wv^T + bv
//   P = softmax(q k^T / 8) ; out = P v Wo^T + bo
// Factorization (R7):
//   F    = Wo . Wv                  (2.1 GF, replaces the 17.2 GF v-proj)
//   Vot  = F . x^T   per batch      ([H][S] bf16; V.Wo^T fold)
//   P_un = exp(q k^T / 8)           (bf16 + atomic fp32 rowsums)
//   out  = (P_un . Vot^T)/rowsum + bfinal,  bfinal = bo + Wo.bv
//   (the Wo.bv column-constant multiplies rowsum and cancels into the bias;
//    per-row score constants cancel in softmax — score path is numerically
//    IDENTICAL to R5/R6, absmax 0.0703 preserved.)
// R6 post-mortem: heterogeneous epilogues in one kernel cost VGPR 80->112 и
// occupancy — dual reverted. F is fused into the Q/K dispatch instead (same
// epilogue path -> no register penalty).
// K-loop: 16x16x32 bf16 MFMA, 128x128 tile, BK=64, global_load_lds width-16,
// xor-swizzled LDS (measured conflict-free), XCD-aware remap, K templated.
// 5 dispatches: cvt_all -> QKF -> Vot -> scores -> final.
// ---------------------------------------------------------------------------

typedef __bf16 bf16x8 __attribute__((ext_vector_type(8)));
typedef float  f32x4  __attribute__((ext_vector_type(4)));

__device__ __forceinline__ unsigned short f32_to_bf16_rne(float f) {
    uint32_t u = __builtin_bit_cast(uint32_t, f);
    uint32_t r = (u + 0x7FFFu + ((u >> 16) & 1u)) >> 16;
    return (unsigned short)r;
}

#define BM 128
#define BN 128
#define BK 64

// ---------------------------------------------------------------------------
// One-dispatch prep, 11544 blocks:
//   [0,8192)        x fp32 -> x16 bf16
//   [8192,11264)    Wq,Wk,Wo straight converts into w16 slots 0..2
//   [11264,11520)   Wv 64x64-tile transpose -> w16 slot 3 (WvT, K-contig)
//   [11520,11536)   bfinal = bo + Wo.bv   (wave-per-16-rows matvec)
//   [11536,11544)   zero rsum
// ---------------------------------------------------------------------------
__global__ __launch_bounds__(256) void cvt_all(
    const float* __restrict__ x,
    const float* __restrict__ Wq, const float* __restrict__ Wk,
    const float* __restrict__ Wo, const float* __restrict__ Wv,
    const float* __restrict__ bv, const float* __restrict__ bo,
    unsigned short* __restrict__ x16, unsigned short* __restrict__ w16,
    float* __restrict__ rsum, float* __restrict__ bfinal)
{
    const int b = blockIdx.x, tid = threadIdx.x;
    if (b < 8192) {
        int i = (b * 256 + tid) * 4;
        float4 v = *(const float4*)(x + i);
        ushort4 o;
        o.x = f32_to_bf16_rne(v.x); o.y = f32_to_bf16_rne(v.y);
        o.z = f32_to_bf16_rne(v.z); o.w = f32_to_bf16_rne(v.w);
        *(ushort4*)(x16 + i) = o;
    } else if (b < 11264) {
        int bb = b - 8192;
        int which = bb >> 10;
        const float* src = which == 0 ? Wq : which == 1 ? Wk : Wo;
        int i = ((bb & 1023) * 256 + tid) * 4;
        float4 v = *(const float4*)(src + i);
        ushort4 o;
        o.x = f32_to_bf16_rne(v.x); o.y = f32_to_bf16_rne(v.y);
        o.z = f32_to_bf16_rne(v.z); o.w = f32_to_bf16_rne(v.w);
        *(ushort4*)(w16 + (size_t)which * 1048576 + i) = o;
    } else if (b < 11520) {
        // transpose one 64x64 tile of Wv into WvT (w16 slot 3)
        __shared__ unsigned short tl[64 * 68];   // [c][r], stride 68
        int t = b - 11264, tr = t >> 4, tc = t & 15;
        #pragma unroll
        for (int it = 0; it < 4; ++it) {
            int r  = it * 16 + (tid >> 4);
            int c0 = (tid & 15) * 4;
            float4 v = *(const float4*)(Wv + (size_t)(tr * 64 + r) * 1024 + tc * 64 + c0);
            tl[(c0 + 0) * 68 + r] = f32_to_bf16_rne(v.x);
            tl[(c0 + 1) * 68 + r] = f32_to_bf16_rne(v.y);
            tl[(c0 + 2) * 68 + r] = f32_to_bf16_rne(v.z);
            tl[(c0 + 3) * 68 + r] = f32_to_bf16_rne(v.w);
        }
        __syncthreads();
        #pragma unroll
        for (int it = 0; it < 4; ++it) {
            int c  = it * 16 + (tid >> 4);
            int r0 = (tid & 15) * 4;
            ushort4 o;
            o.x = tl[c * 68 + r0 + 0]; o.y = tl[c * 68 + r0 + 1];
            o.z = tl[c * 68 + r0 + 2]; o.w = tl[c * 68 + r0 + 3];
            *(ushort4*)(w16 + (size_t)3 * 1048576 + (size_t)(tc * 64 + c) * 1024 + tr * 64 + r0) = o;
        }
    } else if (b < 11536) {
        // bfinal[row] = bo[row] + dot(Wo[row,:], bv)   (fp32, wave per 16 rows)
        int bb = b - 11520;
        int lane = tid & 63, wv_ = tid >> 6;
        int rowBase = bb * 64 + wv_ * 16;
        for (int rr = 0; rr < 16; ++rr) {
            int row = rowBase + rr;
            float partial = 0.f;
            #pragma unroll
            for (int t2 = 0; t2 < 16; ++t2) {
                int h = t2 * 64 + lane;
                partial += Wo[(size_t)row * 1024 + h] * bv[h];
            }
            #pragma unroll
            for (int off = 32; off > 0; off >>= 1)
                partial += __shfl_xor(partial, off, 64);
            if (lane == 0) bfinal[row] = bo[row] + partial;
        }
    } else {
        int i = ((b - 11536) * 256 + tid) * 4;
        *(float4*)(rsum + i) = float4{0.f, 0.f, 0.f, 0.f};
    }
}

// ---------------------------------------------------------------------------
// Shared K-loop: stage A/B 128x64 tiles via global_load_lds(16B) into
// xor-swizzled LDS, 32x MFMA 16x16x32 per k0. KC compile-time; ld == KC.
// ---------------------------------------------------------------------------
template <int KC>
__device__ __forceinline__ void gemm_core(
    const unsigned short* __restrict__ Ab,
    const unsigned short* __restrict__ Bb,
    unsigned short* ldsA, unsigned short* ldsB,
    int mBase, int nBase, int lane, int wave, f32x4 (&acc)[4][4])
{
    const int quad = lane >> 4;
    const int l16  = lane & 15;
    const int wr   = wave >> 1;
    const int wc   = wave & 1;

    for (int k0 = 0; k0 < KC; k0 += BK) {
        #pragma unroll
        for (int i = 0; i < 4; ++i) {
            int base = (i * 4 + wave) * 64;
            int s    = base + lane;
            int row  = s >> 3;
            int col  = ((s ^ (s >> 3)) & 7) * 8;
            __builtin_amdgcn_global_load_lds(
                (const __attribute__((address_space(1))) void*)(Ab + (size_t)(mBase + row) * KC + (size_t)(k0 + col)),
                (__attribute__((address_space(3))) void*)(&ldsA[base * 8]),
                16, 0, 0);
        }
        #pragma unroll
        for (int i = 0; i < 4; ++i) {
            int base = (i * 4 + wave) * 64;
            int s    = base + lane;
            int row  = s >> 3;
            int col  = ((s ^ (s >> 3)) & 7) * 8;
            __builtin_amdgcn_global_load_lds(
                (const __attribute__((address_space(1))) void*)(Bb + (size_t)(nBase + row) * KC + (size_t)(k0 + col)),
                (__attribute__((address_space(3))) void*)(&ldsB[base * 8]),
                16, 0, 0);
        }
        __syncthreads();

        #pragma unroll
        for (int kk = 0; kk < 2; ++kk) {
            bf16x8 af[4], bfv[4];
            #pragma unroll
            for (int mi = 0; mi < 4; ++mi) {
                int r = wr * 64 + mi * 16 + l16;
                int c = kk * 4 + quad;
                af[mi] = *(const bf16x8*)(&ldsA[r * BK + (((c ^ r) & 7) << 3)]);
            }
            #pragma unroll
            for (int ni = 0; ni < 4; ++ni) {
                int r = wc * 64 + ni * 16 + l16;
                int c = kk * 4 + quad;
                bfv[ni] = *(const bf16x8*)(&ldsB[r * BK + (((c ^ r) & 7) << 3)]);
            }
            #pragma unroll
            for (int mi = 0; mi < 4; ++mi)
                #pragma unroll
                for (int ni = 0; ni < 4; ++ni)
                    acc[mi][ni] = __builtin_amdgcn_mfma_f32_16x16x32_bf16(
                        af[mi], bfv[ni], acc[mi][ni], 0, 0, 0);
        }
        __syncthreads();
    }
}

// ---------------------------------------------------------------------------
// Generic z-batched A.Bt^T GEMM (KC compile-time).
// MODE 1: C bf16 [Z][M x N] (+optional bias b0)
// MODE 3: scores: C bf16 = exp(acc*alpha), atomic rowsum[zb*M+row]
// MODE 6: final:  C fp32 = acc / rowsum[zb*M+row] + b0[col]
// ---------------------------------------------------------------------------
template <int MODE, int KC>
__global__ __launch_bounds__(256) void gemm_bt(
    const unsigned short* __restrict__ A,
    const unsigned short* __restrict__ Bt,
    void* __restrict__ C,
    const float* __restrict__ b0, float* __restrict__ rowsum,
    float alpha, int M, int N,
    long long aZ, long long bZ, long long cZ)
{
    __shared__ unsigned short ldsA[BM * BK];
    __shared__ unsigned short ldsB[BN * BK];

    // XCD-aware remap: linear%8 = XCD; each XCD gets a contiguous m-band.
    int G  = gridDim.x * gridDim.y * gridDim.z;
    int l  = blockIdx.x + gridDim.x * (blockIdx.y + gridDim.y * blockIdx.z);
    int perx = G >> 3;
    int idx  = (l & 7) * perx + (l >> 3);
    int NB = gridDim.x, Z = gridDim.z;
    int mb = idx / (NB * Z);
    int rem = idx - mb * (NB * Z);
    int zb = rem / NB;
    int nb = rem - zb * NB;

    const unsigned short* Ab = A  + (size_t)zb * aZ;
    const unsigned short* Bb = Bt + (size_t)zb * bZ;

    const int tid  = threadIdx.x;
    const int lane = tid & 63;
    const int wave = tid >> 6;
    const int quad = lane >> 4;
    const int l16  = lane & 15;
    const int wr   = wave >> 1;
    const int wc   = wave & 1;
    const int mBase = mb * BM;
    const int nBase = nb * BN;

    f32x4 acc[4][4] = {};
    gemm_core<KC>(Ab, Bb, ldsA, ldsB, mBase, nBase, lane, wave, acc);

    // ---- epilogues. C/D layout: col = l16, row = quad*4 + reg ----
    if (MODE == 1) {
        unsigned short* Cz = (unsigned short*)C + (size_t)zb * cZ;
        #pragma unroll
        for (int mi = 0; mi < 4; ++mi)
            #pragma unroll
            for (int ni = 0; ni < 4; ++ni) {
                int col = nBase + wc * 64 + ni * 16 + l16;
                float b = b0 ? b0[col] : 0.f;
                #pragma unroll
                for (int r = 0; r < 4; ++r) {
                    int row = mBase + wr * 64 + mi * 16 + quad * 4 + r;
                    Cz[(size_t)row * N + col] = f32_to_bf16_rne(acc[mi][ni][r] + b);
                }
            }
    } else if (MODE == 3) {
        unsigned short* Pz = (unsigned short*)C + (size_t)zb * cZ;
        float* rs = rowsum + (size_t)zb * M;
        #pragma unroll
        for (int mi = 0; mi < 4; ++mi) {
            #pragma unroll
            for (int r = 0; r < 4; ++r) {
                int row = mBase + wr * 64 + mi * 16 + quad * 4 + r;
                float e[4];
                float partial = 0.f;
                #pragma unroll
                for (int ni = 0; ni < 4; ++ni) {
                    e[ni] = __expf(acc[mi][ni][r] * alpha);
                    partial += e[ni];
                }
                #pragma unroll
                for (int ni = 0; ni < 4; ++ni) {
                    int col = nBase + wc * 64 + ni * 16 + l16;
                    Pz[(size_t)row * N + col] = f32_to_bf16_rne(e[ni]);
                }
                #pragma unroll
                for (int off = 1; off < 16; off <<= 1)
                    partial += __shfl_xor(partial, off, 64);
                if (l16 == 0) atomicAdd(&rs[row], partial);
            }
        }
    } else { // MODE 6
        float* Cz = (float*)C + (size_t)zb * cZ;
        const float* rs = rowsum + (size_t)zb * M;
        #pragma unroll
        for (int mi = 0; mi < 4; ++mi) {
            #pragma unroll
            for (int r = 0; r < 4; ++r) {
                int row = mBase + wr * 64 + mi * 16 + quad * 4 + r;
                float inv = 1.f / rs[row];
                #pragma unroll
                for (int ni = 0; ni < 4; ++ni) {
                    int col = nBase + wc * 64 + ni * 16 + l16;
                    Cz[(size_t)row * N + col] = acc[mi][ni][r] * inv + b0[col];
                }
            }
        }
    }
}

// ---------------------------------------------------------------------------
// Q/K projections + F = Wo.Wv in one dispatch (1088 blocks; identical
// epilogue for every role -> no VGPR penalty). All roles: K=1024, N=1024.
//   idx <  512 : q = x Wq^T + bq        (M=8192)
//   idx < 1024 : k = x Wk^T + bk        (M=8192)
//   else       : F = Wo . (WvT)^T       (M=1024, no bias)
// ---------------------------------------------------------------------------
__global__ __launch_bounds__(256) void gemm_qkf(
    const unsigned short* __restrict__ x16,
    const unsigned short* __restrict__ w16,   // [Wq|Wk|Wo|WvT] x 1048576 elems
    unsigned short* __restrict__ q16,
    unsigned short* __restrict__ k16,
    unsigned short* __restrict__ F16,
    const float* __restrict__ bq, const float* __restrict__ bk)
{
    __shared__ unsigned short ldsA[BM * BK];
    __shared__ unsigned short ldsB[BN * BK];

    int l   = blockIdx.x;                 // 1088 = 8 * 136
    int idx = (l & 7) * 136 + (l >> 3);   // XCD-contiguous

    const unsigned short *Ab, *Bb;
    unsigned short* Cb;
    const float* bias;
    int mBase, nBase;
    if (idx < 1024) {
        int role = idx >> 9;              // 0:q 1:k
        int s    = idx & 511;
        mBase = (s >> 3) * BM; nBase = (s & 7) * BN;
        Ab = x16; Bb = w16 + (size_t)role * 1048576;
        Cb = role ? k16 : q16; bias = role ? bk : bq;
    } else {
        int f = idx - 1024;               // 0..63
        mBase = (f >> 3) * BM; nBase = (f & 7) * BN;
        Ab = w16 + (size_t)2 * 1048576;   // Wo
        Bb = w16 + (size_t)3 * 1048576;   // WvT
        Cb = F16; bias = nullptr;
    }

    const int tid  = threadIdx.x;
    const int lane = tid & 63;
    const int wave = tid >> 6;
    const int quad = lane >> 4;
    const int l16  = lane & 15;
    const int wr   = wave >> 1;
    const int wc   = wave & 1;

    f32x4 acc[4][4] = {};
    gemm_core<1024>(Ab, Bb, ldsA, ldsB, mBase, nBase, lane, wave, acc);

    #pragma unroll
    for (int mi = 0; mi < 4; ++mi)
        #pragma unroll
        for (int ni = 0; ni < 4; ++ni) {
            int col = nBase + wc * 64 + ni * 16 + l16;
            float b = bias ? bias[col] : 0.f;
            #pragma unroll
            for (int r = 0; r < 4; ++r) {
                int row = mBase + wr * 64 + mi * 16 + quad * 4 + r;
                Cb[(size_t)row * 1024 + col] = f32_to_bf16_rne(acc[mi][ni][r] + b);
            }
        }
}

// ---------------------------------------------------------------------------
extern "C" void kernel_launch(void* const* d_in, const int* in_sizes, int n_in,
                              void* d_out, int out_size, void* d_ws, size_t ws_size,
                              hipStream_t stream)
{
    const float* x  = (const float*)d_in[0];
    const float* Wq = (const float*)d_in[1];
    const float* bq = (const float*)d_in[2];
    const float* Wk = (const float*)d_in[3];
    const float* bk = (const float*)d_in[4];
    const float* Wv = (const float*)d_in[5];
    const float* bv = (const float*)d_in[6];
    const float* Wo = (const float*)d_in[7];
    const float* bo = (const float*)d_in[8];
    float* out = (float*)d_out;

    const int S = 4096, H = 1024, Bsz = 2;
    const int M = Bsz * S;   // 8192

    char* p = (char*)d_ws;
    auto alloc = [&](size_t bytes) -> char* {
        char* r = p; p += (bytes + 255) & ~(size_t)255; return r;
    };
    // footprint ~122 MiB (ws >= 153 MiB proven in R2)
    unsigned short* w16  = (unsigned short*)alloc((size_t)4 * H * H * 2);  // Wq|Wk|Wo|WvT
    unsigned short* F16  = (unsigned short*)alloc((size_t)H * H * 2);
    unsigned short* q16  = (unsigned short*)alloc((size_t)M * H * 2);
    unsigned short* k16  = (unsigned short*)alloc((size_t)M * H * 2);
    unsigned short* vot16= (unsigned short*)alloc((size_t)Bsz * H * S * 2); // [B][H][S]
    float*          rsum = (float*)alloc((size_t)M * 4);
    float*          bfin = (float*)alloc((size_t)H * 4);
    // region (64 MB): x16 (16 MB head; read by QKF and Vot, both BEFORE the
    // scores dispatch that overwrites it via p16)
    char* region = alloc((size_t)Bsz * S * S * 2);
    unsigned short* x16 = (unsigned short*)region;
    unsigned short* p16 = (unsigned short*)region;

    // 1) converts + Wv transpose + bfinal + rowsum zeroing
    cvt_all<<<11544, 256, 0, stream>>>(x, Wq, Wk, Wo, Wv, bv, bo,
                                       x16, w16, rsum, bfin);

    // 2) q, k projections + F = Wo.Wv
    gemm_qkf<<<1088, 256, 0, stream>>>(x16, w16, q16, k16, F16, bq, bk);

    // 3) Vot[b] = F . x_b^T  -> bf16 [H][S]
    gemm_bt<1, 1024><<<dim3(S / BN, H / BM, 2), 256, 0, stream>>>(
        F16, x16, vot16, nullptr, nullptr, 1.f, H, S,
        0, (long long)S * H, (long long)H * S);

    // 4) P_un[b] = exp(q k^T / 8) + atomic rowsums
    gemm_bt<3, 1024><<<dim3(S / BN, S / BM, 2), 256, 0, stream>>>(
        q16, k16, p16, nullptr, rsum, 0.125f, S, S,
        (long long)S * H, (long long)S * H, (long long)S * S);

    // 5) out[b] = (P_un . Vot^T)/rowsum + bfinal   (fp32)
    gemm_bt<6, 4096><<<dim3(H / BN, S / BM, 2), 256, 0, stream>>>(
        p16, vot16, out, bfin, rsum, 1.f, S, H,
        (long long)S * S, (long long)H * S, (long long)S * H);
}

// Round 8
// 370.076 us; speedup vs baseline: 1.0840x; 1.0840x over previous
//
#include <hip/hip_runtime.h>
#include <stdint.h>

// ---------------------------------------------------------------------------
// DistributedAttention on MI355X (gfx950)
//   q = x Wq^T + bq ; k = x Wk^T + bk ; v = x Wv^T + bv
//   P = softmax(q k^T / 8) ; out = P v Wo^T + bo
// Factorization (R7, kept):
//   F    = Wo . Wv                  (2.1 GF, replaces the 17.2 GF v-proj)
//   Vot  = F . x^T   per batch      ([H][S] bf16)
//   P_un = exp(q k^T / 8)           (bf16 + atomic fp32 rowsums)
//   out  = (P_un . Vot^T)/rowsum + bfinal,  bfinal = bo + Wo.bv
// R8: (1) revert compile-time-K templating — runtime-K loop (R5 codegen,
//     VGPR 80) was 111 µs vs templated 127 µs for scores; compiler schedules
//     its own loop better than the unrolled variant. (2) 2D XCD supertiling:
//     8 XCDs as 2(m) x 4(n); within an XCD order [zb][nbi][mb-fastest] so the
//     XCD's k-bands (2 MB) stay L2-resident and q streams once -> FETCH cut
//     ~2x on scores/final, shorter vmcnt drains.
// K-loop: 16x16x32 bf16 MFMA, 128x128 tile, BK=64, global_load_lds width-16,
// xor-swizzled LDS (measured conflict-free).
// 5 dispatches: cvt_all -> QKF -> Vot -> scores -> final.
// ---------------------------------------------------------------------------

typedef __bf16 bf16x8 __attribute__((ext_vector_type(8)));
typedef float  f32x4  __attribute__((ext_vector_type(4)));

__device__ __forceinline__ unsigned short f32_to_bf16_rne(float f) {
    uint32_t u = __builtin_bit_cast(uint32_t, f);
    uint32_t r = (u + 0x7FFFu + ((u >> 16) & 1u)) >> 16;
    return (unsigned short)r;
}

#define BM 128
#define BN 128
#define BK 64

// ---------------------------------------------------------------------------
// One-dispatch prep, 11544 blocks:
//   [0,8192)        x fp32 -> x16 bf16
//   [8192,11264)    Wq,Wk,Wo straight converts into w16 slots 0..2
//   [11264,11520)   Wv 64x64-tile transpose -> w16 slot 3 (WvT, K-contig)
//   [11520,11536)   bfinal = bo + Wo.bv   (wave-per-16-rows matvec)
//   [11536,11544)   zero rsum
// ---------------------------------------------------------------------------
__global__ __launch_bounds__(256) void cvt_all(
    const float* __restrict__ x,
    const float* __restrict__ Wq, const float* __restrict__ Wk,
    const float* __restrict__ Wo, const float* __restrict__ Wv,
    const float* __restrict__ bv, const float* __restrict__ bo,
    unsigned short* __restrict__ x16, unsigned short* __restrict__ w16,
    float* __restrict__ rsum, float* __restrict__ bfinal)
{
    const int b = blockIdx.x, tid = threadIdx.x;
    if (b < 8192) {
        int i = (b * 256 + tid) * 4;
        float4 v = *(const float4*)(x + i);
        ushort4 o;
        o.x = f32_to_bf16_rne(v.x); o.y = f32_to_bf16_rne(v.y);
        o.z = f32_to_bf16_rne(v.z); o.w = f32_to_bf16_rne(v.w);
        *(ushort4*)(x16 + i) = o;
    } else if (b < 11264) {
        int bb = b - 8192;
        int which = bb >> 10;
        const float* src = which == 0 ? Wq : which == 1 ? Wk : Wo;
        int i = ((bb & 1023) * 256 + tid) * 4;
        float4 v = *(const float4*)(src + i);
        ushort4 o;
        o.x = f32_to_bf16_rne(v.x); o.y = f32_to_bf16_rne(v.y);
        o.z = f32_to_bf16_rne(v.z); o.w = f32_to_bf16_rne(v.w);
        *(ushort4*)(w16 + (size_t)which * 1048576 + i) = o;
    } else if (b < 11520) {
        // transpose one 64x64 tile of Wv into WvT (w16 slot 3)
        __shared__ unsigned short tl[64 * 68];   // [c][r], stride 68
        int t = b - 11264, tr = t >> 4, tc = t & 15;
        #pragma unroll
        for (int it = 0; it < 4; ++it) {
            int r  = it * 16 + (tid >> 4);
            int c0 = (tid & 15) * 4;
            float4 v = *(const float4*)(Wv + (size_t)(tr * 64 + r) * 1024 + tc * 64 + c0);
            tl[(c0 + 0) * 68 + r] = f32_to_bf16_rne(v.x);
            tl[(c0 + 1) * 68 + r] = f32_to_bf16_rne(v.y);
            tl[(c0 + 2) * 68 + r] = f32_to_bf16_rne(v.z);
            tl[(c0 + 3) * 68 + r] = f32_to_bf16_rne(v.w);
        }
        __syncthreads();
        #pragma unroll
        for (int it = 0; it < 4; ++it) {
            int c  = it * 16 + (tid >> 4);
            int r0 = (tid & 15) * 4;
            ushort4 o;
            o.x = tl[c * 68 + r0 + 0]; o.y = tl[c * 68 + r0 + 1];
            o.z = tl[c * 68 + r0 + 2]; o.w = tl[c * 68 + r0 + 3];
            *(ushort4*)(w16 + (size_t)3 * 1048576 + (size_t)(tc * 64 + c) * 1024 + tr * 64 + r0) = o;
        }
    } else if (b < 11536) {
        // bfinal[row] = bo[row] + dot(Wo[row,:], bv)   (fp32, wave per 16 rows)
        int bb = b - 11520;
        int lane = tid & 63, wv_ = tid >> 6;
        int rowBase = bb * 64 + wv_ * 16;
        for (int rr = 0; rr < 16; ++rr) {
            int row = rowBase + rr;
            float partial = 0.f;
            #pragma unroll
            for (int t2 = 0; t2 < 16; ++t2) {
                int h = t2 * 64 + lane;
                partial += Wo[(size_t)row * 1024 + h] * bv[h];
            }
            #pragma unroll
            for (int off = 32; off > 0; off >>= 1)
                partial += __shfl_xor(partial, off, 64);
            if (lane == 0) bfinal[row] = bo[row] + partial;
        }
    } else {
        int i = ((b - 11536) * 256 + tid) * 4;
        *(float4*)(rsum + i) = float4{0.f, 0.f, 0.f, 0.f};
    }
}

// ---------------------------------------------------------------------------
// Shared K-loop (runtime K — the compiler pipelines this better than the
// fully-unrolled compile-time-K variant: 111 vs 127 µs on scores, R5 vs R7).
// Stage A/B 128x64 tiles via global_load_lds(16B) into xor-swizzled LDS,
// 32x MFMA 16x16x32 per k0. ld == K.
// ---------------------------------------------------------------------------
__device__ __forceinline__ void gemm_core(
    const unsigned short* __restrict__ Ab,
    const unsigned short* __restrict__ Bb,
    unsigned short* ldsA, unsigned short* ldsB,
    int mBase, int nBase, int lane, int wave, int K, f32x4 (&acc)[4][4])
{
    const int quad = lane >> 4;
    const int l16  = lane & 15;
    const int wr   = wave >> 1;
    const int wc   = wave & 1;

    for (int k0 = 0; k0 < K; k0 += BK) {
        #pragma unroll
        for (int i = 0; i < 4; ++i) {
            int base = (i * 4 + wave) * 64;
            int s    = base + lane;
            int row  = s >> 3;
            int col  = ((s ^ (s >> 3)) & 7) * 8;
            __builtin_amdgcn_global_load_lds(
                (const __attribute__((address_space(1))) void*)(Ab + (size_t)(mBase + row) * K + (size_t)(k0 + col)),
                (__attribute__((address_space(3))) void*)(&ldsA[base * 8]),
                16, 0, 0);
        }
        #pragma unroll
        for (int i = 0; i < 4; ++i) {
            int base = (i * 4 + wave) * 64;
            int s    = base + lane;
            int row  = s >> 3;
            int col  = ((s ^ (s >> 3)) & 7) * 8;
            __builtin_amdgcn_global_load_lds(
                (const __attribute__((address_space(1))) void*)(Bb + (size_t)(nBase + row) * K + (size_t)(k0 + col)),
                (__attribute__((address_space(3))) void*)(&ldsB[base * 8]),
                16, 0, 0);
        }
        __syncthreads();

        #pragma unroll
        for (int kk = 0; kk < 2; ++kk) {
            bf16x8 af[4], bfv[4];
            #pragma unroll
            for (int mi = 0; mi < 4; ++mi) {
                int r = wr * 64 + mi * 16 + l16;
                int c = kk * 4 + quad;
                af[mi] = *(const bf16x8*)(&ldsA[r * BK + (((c ^ r) & 7) << 3)]);
            }
            #pragma unroll
            for (int ni = 0; ni < 4; ++ni) {
                int r = wc * 64 + ni * 16 + l16;
                int c = kk * 4 + quad;
                bfv[ni] = *(const bf16x8*)(&ldsB[r * BK + (((c ^ r) & 7) << 3)]);
            }
            #pragma unroll
            for (int mi = 0; mi < 4; ++mi)
                #pragma unroll
                for (int ni = 0; ni < 4; ++ni)
                    acc[mi][ni] = __builtin_amdgcn_mfma_f32_16x16x32_bf16(
                        af[mi], bfv[ni], acc[mi][ni], 0, 0, 0);
        }
        __syncthreads();
    }
}

// ---------------------------------------------------------------------------
// Generic z-batched A.Bt^T GEMM.
// 2D XCD supertiling: 8 XCDs as 2(m) x 4(n); within an XCD, blocks ordered
// [zb][nbi][mb fastest] so the XCD's NBX k-bands stay L2-resident while the
// q/m operand streams. Requires gridDim.y % 2 == 0, gridDim.x % 4 == 0.
// MODE 1: C bf16 [Z][M x N] (+optional bias b0)
// MODE 3: scores: C bf16 = exp(acc*alpha), atomic rowsum[zb*M+row]
// MODE 6: final:  C fp32 = acc / rowsum[zb*M+row] + b0[col]
// ---------------------------------------------------------------------------
template <int MODE>
__global__ __launch_bounds__(256) void gemm_bt(
    const unsigned short* __restrict__ A,
    const unsigned short* __restrict__ Bt,
    void* __restrict__ C,
    const float* __restrict__ b0, float* __restrict__ rowsum,
    float alpha, int M, int N, int K,
    long long aZ, long long bZ, long long cZ)
{
    __shared__ unsigned short ldsA[BM * BK];
    __shared__ unsigned short ldsB[BN * BK];

    const int NB = gridDim.x, MBt = gridDim.y;
    int l  = blockIdx.x + gridDim.x * (blockIdx.y + gridDim.y * blockIdx.z);
    int xcd = l & 7;
    int t   = l >> 3;
    int MBX = MBt >> 1;          // m-tiles per XCD
    int NBX = NB >> 2;           // n-tiles per XCD
    int mbl = t % MBX;
    int r1  = t / MBX;
    int nbi = r1 % NBX;
    int zb  = r1 / NBX;
    int mb  = (xcd >> 2) * MBX + mbl;
    int nb  = (xcd & 3) * NBX + nbi;

    const unsigned short* Ab = A  + (size_t)zb * aZ;
    const unsigned short* Bb = Bt + (size_t)zb * bZ;

    const int tid  = threadIdx.x;
    const int lane = tid & 63;
    const int wave = tid >> 6;
    const int quad = lane >> 4;
    const int l16  = lane & 15;
    const int wr   = wave >> 1;
    const int wc   = wave & 1;
    const int mBase = mb * BM;
    const int nBase = nb * BN;

    f32x4 acc[4][4] = {};
    gemm_core(Ab, Bb, ldsA, ldsB, mBase, nBase, lane, wave, K, acc);

    // ---- epilogues. C/D layout: col = l16, row = quad*4 + reg ----
    if (MODE == 1) {
        unsigned short* Cz = (unsigned short*)C + (size_t)zb * cZ;
        #pragma unroll
        for (int mi = 0; mi < 4; ++mi)
            #pragma unroll
            for (int ni = 0; ni < 4; ++ni) {
                int col = nBase + wc * 64 + ni * 16 + l16;
                float b = b0 ? b0[col] : 0.f;
                #pragma unroll
                for (int r = 0; r < 4; ++r) {
                    int row = mBase + wr * 64 + mi * 16 + quad * 4 + r;
                    Cz[(size_t)row * N + col] = f32_to_bf16_rne(acc[mi][ni][r] + b);
                }
            }
    } else if (MODE == 3) {
        unsigned short* Pz = (unsigned short*)C + (size_t)zb * cZ;
        float* rs = rowsum + (size_t)zb * M;
        #pragma unroll
        for (int mi = 0; mi < 4; ++mi) {
            #pragma unroll
            for (int r = 0; r < 4; ++r) {
                int row = mBase + wr * 64 + mi * 16 + quad * 4 + r;
                float e[4];
                float partial = 0.f;
                #pragma unroll
                for (int ni = 0; ni < 4; ++ni) {
                    e[ni] = __expf(acc[mi][ni][r] * alpha);
                    partial += e[ni];
                }
                #pragma unroll
                for (int ni = 0; ni < 4; ++ni) {
                    int col = nBase + wc * 64 + ni * 16 + l16;
                    Pz[(size_t)row * N + col] = f32_to_bf16_rne(e[ni]);
                }
                #pragma unroll
                for (int off = 1; off < 16; off <<= 1)
                    partial += __shfl_xor(partial, off, 64);
                if (l16 == 0) atomicAdd(&rs[row], partial);
            }
        }
    } else { // MODE 6
        float* Cz = (float*)C + (size_t)zb * cZ;
        const float* rs = rowsum + (size_t)zb * M;
        #pragma unroll
        for (int mi = 0; mi < 4; ++mi) {
            #pragma unroll
            for (int r = 0; r < 4; ++r) {
                int row = mBase + wr * 64 + mi * 16 + quad * 4 + r;
                float inv = 1.f / rs[row];
                #pragma unroll
                for (int ni = 0; ni < 4; ++ni) {
                    int col = nBase + wc * 64 + ni * 16 + l16;
                    Cz[(size_t)row * N + col] = acc[mi][ni][r] * inv + b0[col];
                }
            }
        }
    }
}

// ---------------------------------------------------------------------------
// Q/K projections + F = Wo.Wv in one dispatch (1088 blocks; identical
// epilogue for every role -> no VGPR penalty). All roles: K=1024, N=1024.
//   idx <  512 : q = x Wq^T + bq        (M=8192)
//   idx < 1024 : k = x Wk^T + bk        (M=8192)
//   else       : F = Wo . (WvT)^T       (M=1024, no bias)
// ---------------------------------------------------------------------------
__global__ __launch_bounds__(256) void gemm_qkf(
    const unsigned short* __restrict__ x16,
    const unsigned short* __restrict__ w16,   // [Wq|Wk|Wo|WvT] x 1048576 elems
    unsigned short* __restrict__ q16,
    unsigned short* __restrict__ k16,
    unsigned short* __restrict__ F16,
    const float* __restrict__ bq, const float* __restrict__ bk)
{
    __shared__ unsigned short ldsA[BM * BK];
    __shared__ unsigned short ldsB[BN * BK];

    int l   = blockIdx.x;                 // 1088 = 8 * 136
    int idx = (l & 7) * 136 + (l >> 3);   // XCD-contiguous

    const unsigned short *Ab, *Bb;
    unsigned short* Cb;
    const float* bias;
    int mBase, nBase;
    if (idx < 1024) {
        int role = idx >> 9;              // 0:q 1:k
        int s    = idx & 511;
        mBase = (s >> 3) * BM; nBase = (s & 7) * BN;
        Ab = x16; Bb = w16 + (size_t)role * 1048576;
        Cb = role ? k16 : q16; bias = role ? bk : bq;
    } else {
        int f = idx - 1024;               // 0..63
        mBase = (f >> 3) * BM; nBase = (f & 7) * BN;
        Ab = w16 + (size_t)2 * 1048576;   // Wo
        Bb = w16 + (size_t)3 * 1048576;   // WvT
        Cb = F16; bias = nullptr;
    }

    const int tid  = threadIdx.x;
    const int lane = tid & 63;
    const int wave = tid >> 6;
    const int quad = lane >> 4;
    const int l16  = lane & 15;
    const int wr   = wave >> 1;
    const int wc   = wave & 1;

    f32x4 acc[4][4] = {};
    gemm_core(Ab, Bb, ldsA, ldsB, mBase, nBase, lane, wave, 1024, acc);

    #pragma unroll
    for (int mi = 0; mi < 4; ++mi)
        #pragma unroll
        for (int ni = 0; ni < 4; ++ni) {
            int col = nBase + wc * 64 + ni * 16 + l16;
            float b = bias ? bias[col] : 0.f;
            #pragma unroll
            for (int r = 0; r < 4; ++r) {
                int row = mBase + wr * 64 + mi * 16 + quad * 4 + r;
                Cb[(size_t)row * 1024 + col] = f32_to_bf16_rne(acc[mi][ni][r] + b);
            }
        }
}

// ---------------------------------------------------------------------------
extern "C" void kernel_launch(void* const* d_in, const int* in_sizes, int n_in,
                              void* d_out, int out_size, void* d_ws, size_t ws_size,
                              hipStream_t stream)
{
    const float* x  = (const float*)d_in[0];
    const float* Wq = (const float*)d_in[1];
    const float* bq = (const float*)d_in[2];
    const float* Wk = (const float*)d_in[3];
    const float* bk = (const float*)d_in[4];
    const float* Wv = (const float*)d_in[5];
    const float* bv = (const float*)d_in[6];
    const float* Wo = (const float*)d_in[7];
    const float* bo = (const float*)d_in[8];
    float* out = (float*)d_out;

    const int S = 4096, H = 1024, Bsz = 2;
    const int M = Bsz * S;   // 8192

    char* p = (char*)d_ws;
    auto alloc = [&](size_t bytes) -> char* {
        char* r = p; p += (bytes + 255) & ~(size_t)255; return r;
    };
    // footprint ~122 MiB (ws >= 153 MiB proven in R2)
    unsigned short* w16  = (unsigned short*)alloc((size_t)4 * H * H * 2);  // Wq|Wk|Wo|WvT
    unsigned short* F16  = (unsigned short*)alloc((size_t)H * H * 2);
    unsigned short* q16  = (unsigned short*)alloc((size_t)M * H * 2);
    unsigned short* k16  = (unsigned short*)alloc((size_t)M * H * 2);
    unsigned short* vot16= (unsigned short*)alloc((size_t)Bsz * H * S * 2); // [B][H][S]
    float*          rsum = (float*)alloc((size_t)M * 4);
    float*          bfin = (float*)alloc((size_t)H * 4);
    // region (64 MB): x16 (16 MB head; read by QKF and Vot, both BEFORE the
    // scores dispatch that overwrites it via p16)
    char* region = alloc((size_t)Bsz * S * S * 2);
    unsigned short* x16 = (unsigned short*)region;
    unsigned short* p16 = (unsigned short*)region;

    // 1) converts + Wv transpose + bfinal + rowsum zeroing
    cvt_all<<<11544, 256, 0, stream>>>(x, Wq, Wk, Wo, Wv, bv, bo,
                                       x16, w16, rsum, bfin);

    // 2) q, k projections + F = Wo.Wv
    gemm_qkf<<<1088, 256, 0, stream>>>(x16, w16, q16, k16, F16, bq, bk);

    // 3) Vot[b] = F . x_b^T  -> bf16 [H][S]
    gemm_bt<1><<<dim3(S / BN, H / BM, 2), 256, 0, stream>>>(
        F16, x16, vot16, nullptr, nullptr, 1.f, H, S, 1024,
        0, (long long)S * H, (long long)H * S);

    // 4) P_un[b] = exp(q k^T / 8) + atomic rowsums
    gemm_bt<3><<<dim3(S / BN, S / BM, 2), 256, 0, stream>>>(
        q16, k16, p16, nullptr, rsum, 0.125f, S, S, 1024,
        (long long)S * H, (long long)S * H, (long long)S * S);

    // 5) out[b] = (P_un . Vot^T)/rowsum + bfinal   (fp32)
    gemm_bt<6><<<dim3(H / BN, S / BM, 2), 256, 0, stream>>>(
        p16, vot16, out, bfin, rsum, 1.f, S, H, 4096,
        (long long)S * S, (long long)H * S, (long long)S * H);
}